// Round 6
// baseline (152.343 us; speedup 1.0000x reference)
//
#include <hip/hip_runtime.h>
#include <math.h>

#define TOPK 4
#define BLOCK 256

// One node per thread, zero LDS, 4-deep MLP. Round-3 evidence: this layout
// gets 67% occupancy and zero conflicts but the compiler allocated 20 VGPRs
// and issued loads 2-at-a-time with an immediate full drain -> pure exposed
// latency. Fix: each iteration issues 4 independent float4 loads (16 edges)
// before any use, forcing ~16 live floats (VGPR ~48) and progressive
// vmcnt(3/2/1/0) waits. 8 waves/SIMD x 4 quads = 32 outstanding loads per
// SIMD; per-thread trip counts differ -> stalls decorrelate (unlike the
// block-synchronized LDS staging rounds).
__global__ __launch_bounds__(BLOCK, 8) void segment_top4_kernel(
    const int* __restrict__ row_ptr,
    const float* __restrict__ scores,
    float* __restrict__ vals_out,   // [N,4] float32
    float* __restrict__ idx_out,    // [N,4] indices as float32
    int n_nodes, int n_edges)
{
    int node = blockIdx.x * BLOCK + threadIdx.x;
    if (node >= n_nodes) return;

    int sb = row_ptr[node];
    int se = row_ptr[node + 1];

    // Top-4 insert: strict '>' while scanning in increasing edge order
    // == reference tie-break (score desc, index asc). -inf never inserts.
    float v0 = -INFINITY, v1 = -INFINITY, v2 = -INFINITY, v3 = -INFINITY;
    int   i0 = -1, i1 = -1, i2 = -1, i3 = -1;
    auto ins = [&](float s, int ei) {
        bool g0 = s > v0, g1 = s > v1, g2 = s > v2, g3 = s > v3;
        v3 = g3 ? (g2 ? v2 : s) : v3;  i3 = g3 ? (g2 ? i2 : ei) : i3;
        v2 = g2 ? (g1 ? v1 : s) : v2;  i2 = g2 ? (g1 ? i1 : ei) : i2;
        v1 = g1 ? (g0 ? v0 : s) : v1;  i1 = g1 ? (g0 ? i0 : ei) : i1;
        v0 = g0 ? s : v0;              i0 = g0 ? ei : i0;
    };

    unsigned rng = (unsigned)(se - sb);   // live iff (unsigned)(ei - sb) < rng
    int e0 = sb & ~3;                     // 16B-aligned quad start

    if (se <= n_edges - 16) {
        // Fast path: every load of every 16-edge batch is in-bounds by
        // construction (max read index e+15 <= se+14 <= n_edges-2).
        for (int e = e0; e < se; e += 16) {
            // 4 independent quad loads -- issued back-to-back, no waits.
            float4 qa = *(const float4*)(scores + e);
            float4 qb = *(const float4*)(scores + e + 4);
            float4 qc = *(const float4*)(scores + e + 8);
            float4 qd = *(const float4*)(scores + e + 12);
            unsigned off = (unsigned)(e - sb);   // wraps below sb -> masked
            ins(off       < rng ? qa.x : -INFINITY, e);
            ins(off +  1u < rng ? qa.y : -INFINITY, e + 1);
            ins(off +  2u < rng ? qa.z : -INFINITY, e + 2);
            ins(off +  3u < rng ? qa.w : -INFINITY, e + 3);
            ins(off +  4u < rng ? qb.x : -INFINITY, e + 4);
            ins(off +  5u < rng ? qb.y : -INFINITY, e + 5);
            ins(off +  6u < rng ? qb.z : -INFINITY, e + 6);
            ins(off +  7u < rng ? qb.w : -INFINITY, e + 7);
            ins(off +  8u < rng ? qc.x : -INFINITY, e + 8);
            ins(off +  9u < rng ? qc.y : -INFINITY, e + 9);
            ins(off + 10u < rng ? qc.z : -INFINITY, e + 10);
            ins(off + 11u < rng ? qc.w : -INFINITY, e + 11);
            ins(off + 12u < rng ? qd.x : -INFINITY, e + 12);
            ins(off + 13u < rng ? qd.y : -INFINITY, e + 13);
            ins(off + 14u < rng ? qd.z : -INFINITY, e + 14);
            ins(off + 15u < rng ? qd.w : -INFINITY, e + 15);
        }
    } else {
        // Tail path (last few nodes only): clamp quad starts to the last
        // in-bounds aligned quad; a clamped quad shifts its window backward,
        // so also mask elements below the quad's intended start (prevents
        // duplicate insertion). Live-element order stays strictly
        // increasing, preserving the tie-break. (Verified in round 3.)
        int ce = n_edges - 4;
        for (int e = e0; e < se; e += 16) {
#pragma unroll
            for (int q = 0; q < 4; ++q) {
                int qs = e + q * 4;
                int a  = min(qs, ce);
                float4 qq = *(const float4*)(scores + a);
                auto m = [&](int ei) -> bool {
                    return ((unsigned)(ei - sb) < rng) && (ei >= qs);
                };
                ins(m(a)     ? qq.x : -INFINITY, a);
                ins(m(a + 1) ? qq.y : -INFINITY, a + 1);
                ins(m(a + 2) ? qq.z : -INFINITY, a + 2);
                ins(m(a + 3) ? qq.w : -INFINITY, a + 3);
            }
        }
    }

    // ---- store (coalesced: consecutive threads -> consecutive float4) ----
    float4 vo, io;
    vo.x = v0; vo.y = v1; vo.z = v2; vo.w = v3;
    io.x = (float)i0; io.y = (float)i1; io.z = (float)i2; io.w = (float)i3;
    *(float4*)(vals_out + (size_t)node * 4) = vo;
    *(float4*)(idx_out + (size_t)node * 4) = io;
}

extern "C" void kernel_launch(void* const* d_in, const int* in_sizes, int n_in,
                              void* d_out, int out_size, void* d_ws, size_t ws_size,
                              hipStream_t stream)
{
    const int*   row_ptr = (const int*)d_in[0];
    const float* scores  = (const float*)d_in[1];
    int n_nodes = in_sizes[0] - 1;
    int n_edges = in_sizes[1];

    float* out      = (float*)d_out;
    float* vals_out = out;                           // first N*4 floats
    float* idx_out  = out + (size_t)n_nodes * TOPK;  // next N*4 floats (idx as f32)

    int grid = (n_nodes + BLOCK - 1) / BLOCK;
    segment_top4_kernel<<<grid, BLOCK, 0, stream>>>(
        row_ptr, scores, vals_out, idx_out, n_nodes, n_edges);
}